// Round 12
// baseline (103.328 us; speedup 1.0000x reference)
//
#include <hip/hip_runtime.h>

typedef __attribute__((ext_vector_type(8))) short short8;
typedef __attribute__((ext_vector_type(16))) float floatx16;

// B1 frag layout (hi-only): per sid, q = (ds*9 + j)*4 + nc  (ds<16, j<9, nc<4)
//   uint4 slot = q*64 + l
// B2 frag layout (hi-only): per sid, q2 = (w*9 + j)*2 + nc (w<8, nc<2); slot = q2*64 + l

__device__ __forceinline__ unsigned short f2bf(float f) {
  union { float f; unsigned u; } v; v.f = f;
  unsigned r = v.u + 0x7fffu + ((v.u >> 16) & 1u);
  return (unsigned short)(r >> 16);
}

__global__ __launch_bounds__(512) void prep_frags(
    const float* __restrict__ bw1x, const float* __restrict__ sw1x,
    const float* __restrict__ bb1x, const float* __restrict__ sb1x,
    const float* __restrict__ bw2x, const float* __restrict__ sw2x,
    const float* __restrict__ bb2x, const float* __restrict__ sb2x,
    const float* __restrict__ bw1y, const float* __restrict__ sw1y,
    const float* __restrict__ bb1y, const float* __restrict__ sb1y,
    const float* __restrict__ bw2y, const float* __restrict__ sw2y,
    const float* __restrict__ bb2y, const float* __restrict__ sb2y,
    uint4* __restrict__ B1fx, uint4* __restrict__ B1fy,
    uint4* __restrict__ B2fx, uint4* __restrict__ B2fy,
    float* __restrict__ b1x, float* __restrict__ b1y,
    float* __restrict__ b2x, float* __restrict__ b2y,
    int* __restrict__ cnts)
{
  int idx = blockIdx.x * 512 + threadIdx.x;
  if (idx < 2 * 36864) {                       // B1: 2 sids x 576 q x 64 l
    int sid = idx / 36864;
    int rem = idx - sid * 36864;
    int q = rem >> 6, l = rem & 63;
    int nc = q & 3, t9 = q >> 2;
    int j = t9 % 9, ds = t9 / 9;
    const float* bw = sid ? bw1y : bw1x;
    const float* sw = sid ? sw1y : sw1x;
    uint4* dst = sid ? B1fy : B1fx;
    int o = nc * 32 + (l & 31);
    int dbase = ds * 16 + (l >> 5) * 8;
    unsigned short eh[8];
    #pragma unroll
    for (int i = 0; i < 8; ++i) {
      int d = dbase + i;
      float wv = (j == 0) ? bw[o * 256 + d] : sw[o * 2048 + d * 8 + (j - 1)];
      eh[i] = f2bf(wv);
    }
    uint4 oh;
    oh.x = (unsigned)eh[0] | ((unsigned)eh[1] << 16);
    oh.y = (unsigned)eh[2] | ((unsigned)eh[3] << 16);
    oh.z = (unsigned)eh[4] | ((unsigned)eh[5] << 16);
    oh.w = (unsigned)eh[6] | ((unsigned)eh[7] << 16);
    dst[q * 64 + l] = oh;
  } else if (idx < 2 * 36864 + 2 * 9216) {     // B2: 2 sids x 144 q2 x 64 l
    int i2 = idx - 2 * 36864;
    int sid = i2 / 9216;
    int rem = i2 - sid * 9216;
    int q2 = rem >> 6, l = rem & 63;
    int nc = q2 & 1, t9 = q2 >> 1;
    int j = t9 % 9, w = t9 / 9;
    const float* bw = sid ? bw2y : bw2x;
    const float* sw = sid ? sw2y : sw2x;
    uint4* dst = sid ? B2fy : B2fx;
    int o = nc * 32 + (l & 31);
    int dbase = w * 16 + (l >> 5) * 8;
    unsigned short eh[8];
    #pragma unroll
    for (int i = 0; i < 8; ++i) {
      int d = dbase + i;
      float wv = (j == 0) ? bw[o * 128 + d] : sw[o * 1024 + d * 8 + (j - 1)];
      eh[i] = f2bf(wv);
    }
    uint4 oh;
    oh.x = (unsigned)eh[0] | ((unsigned)eh[1] << 16);
    oh.y = (unsigned)eh[2] | ((unsigned)eh[3] << 16);
    oh.z = (unsigned)eh[4] | ((unsigned)eh[5] << 16);
    oh.w = (unsigned)eh[6] | ((unsigned)eh[7] << 16);
    dst[q2 * 64 + l] = oh;
  } else {
    int i2 = idx - (2 * 36864 + 2 * 9216);
    if (i2 < 128)      b1x[i2]       = bb1x[i2]       + sb1x[i2];
    else if (i2 < 256) b1y[i2 - 128] = bb1y[i2 - 128] + sb1y[i2 - 128];
    else if (i2 < 320) b2x[i2 - 256] = bb2x[i2 - 256] + sb2x[i2 - 256];
    else if (i2 < 384) b2y[i2 - 320] = bb2y[i2 - 320] + sb2y[i2 - 320];
    else if (i2 < 384 + 260) cnts[i2 - 384] = 0;   // cnt_tile[256] + cnt_batch[4]
  }
}

// ---------- fused: block = (sid, 32-row tile m, K-half kh); 256 thr, 4 waves ----
// Layer1 half-K partial -> hp; 2nd finisher per tile does layer2 + final dot.
__global__ __launch_bounds__(256, 4) void fused_kernel(
    const float* __restrict__ Xx, const float* __restrict__ Xy,
    const uint4* __restrict__ B1fx, const uint4* __restrict__ B1fy,
    const uint4* __restrict__ B2fx, const uint4* __restrict__ B2fy,
    const float* __restrict__ b1x_, const float* __restrict__ b1y_,
    const float* __restrict__ b2x_, const float* __restrict__ b2y_,
    const float* __restrict__ finw, const float* __restrict__ finb,
    float* __restrict__ hp, float* __restrict__ partial,
    int* __restrict__ cnt_tile, int* __restrict__ cnt_batch,
    float* __restrict__ out)
{
  __shared__ __align__(16) char smem[33824];
  float* xsh  = (float*)smem;               // 32*132 floats = 16896 B
  float* S0   = (float*)smem;               // 16 KB (alias, after xr read)
  float* S1   = (float*)(smem + 16896);     // 16 KB
  float* redw = (float*)(smem + 33280);     // 4 floats
  int*   flag = (int*)(smem + 33296);

  const int t    = threadIdx.x;
  const int bid  = blockIdx.x;
  const int sid  = bid >> 8;
  const int m    = (bid >> 1) & 127;
  const int kh   = bid & 1;
  const int wave = t >> 6;
  const int l    = t & 63;
  const int lc   = l & 31;
  const int lk   = l >> 5;
  const int tile = sid * 128 + m;

  const float* X  = sid ? Xy : Xx;
  const uint4* B1 = sid ? B1fy : B1fx;
  const uint4* B2 = sid ? B2fy : B2fx;
  const float* b1 = sid ? b1y_ : b1x_;
  const float* b2 = sid ? b2y_ : b2x_;

  // ---- stage x tile: 32 rows x 128 cols (this K-half), coalesced ----
  {
    int row = t >> 3, col = (t & 7) * 16;
    const float* src = X + (size_t)(m * 32 + row) * 256 + kh * 128 + col;
    #pragma unroll
    for (int q = 0; q < 4; ++q)
      *(float4*)(xsh + row * 132 + col + q * 4) = *(const float4*)(src + q * 4);
  }
  __syncthreads();

  // per-lane A data: row lc, local dims wave*32 + lk*8 + [0,8) and +16
  float xr0[8], xr1[8];
  {
    int cb = wave * 32 + lk * 8;
    float4 v0 = *(const float4*)(xsh + lc * 132 + cb);
    float4 v1 = *(const float4*)(xsh + lc * 132 + cb + 4);
    float4 u0 = *(const float4*)(xsh + lc * 132 + cb + 16);
    float4 u1 = *(const float4*)(xsh + lc * 132 + cb + 20);
    xr0[0]=v0.x; xr0[1]=v0.y; xr0[2]=v0.z; xr0[3]=v0.w;
    xr0[4]=v1.x; xr0[5]=v1.y; xr0[6]=v1.z; xr0[7]=v1.w;
    xr1[0]=u0.x; xr1[1]=u0.y; xr1[2]=u0.z; xr1[3]=u0.w;
    xr1[4]=u1.x; xr1[5]=u1.y; xr1[6]=u1.z; xr1[7]=u1.w;
  }
  __syncthreads();   // xsh dead; S0 free

  // ================= layer 1 half-K: 18 steps (9 j x 2 local ds) ==============
  floatx16 acc[4] = {};

  auto loadB1 = [&](int s, uint4* bf) {
    int j = s >> 1, ds = kh * 8 + wave * 2 + (s & 1);
    const uint4* bp = B1 + (size_t)((ds * 9 + j) * 4) * 64 + l;
    #pragma unroll
    for (int nc = 0; nc < 4; ++nc) bf[nc] = bp[nc * 64];
  };
  auto computeB1 = [&](int s, const uint4* bf) {
    int j = s >> 1;
    const float* xr = (s & 1) ? xr1 : xr0;
    float f[8];
    if (j == 0) {
      #pragma unroll
      for (int i = 0; i < 8; ++i)
        f[i] = __fdividef(xr[i], 1.f + __expf(-xr[i]));
    } else {
      float g = -2.f + (float)(j - 1) * (4.f / 7.f);
      #pragma unroll
      for (int i = 0; i < 8; ++i) {
        float z = (xr[i] - g) * 1.75f;
        f[i] = __expf(-z * z);
      }
    }
    short8 a;
    #pragma unroll
    for (int i = 0; i < 8; ++i) a[i] = (short)f2bf(f[i]);
    #pragma unroll
    for (int nc = 0; nc < 4; ++nc) {
      short8 bh = __builtin_bit_cast(short8, bf[nc]);
      acc[nc] = __builtin_amdgcn_mfma_f32_32x32x16_bf16(a, bh, acc[nc], 0, 0, 0);
    }
  };

  {
    uint4 bfE[4], bfO[4];
    loadB1(0, bfE);
    #pragma unroll 1
    for (int s = 0; s < 18; s += 2) {
      loadB1(s + 1, bfO);
      computeB1(s, bfE);
      if (s + 2 < 18) loadB1(s + 2, bfE);
      computeB1(s + 1, bfO);
    }
  }

  // ---- cross-wave reduction over 4 waves (32x128 half-K partial) ----
  auto st = [&](float* Sb) {
    #pragma unroll
    for (int nc = 0; nc < 4; ++nc)
      #pragma unroll
      for (int r = 0; r < 16; ++r) {
        int row = (r & 3) + 8 * (r >> 2) + 4 * lk;
        Sb[row * 128 + nc * 32 + lc] = acc[nc][r];
      }
  };
  auto ad = [&](const float* Sb) {
    #pragma unroll
    for (int nc = 0; nc < 4; ++nc)
      #pragma unroll
      for (int r = 0; r < 16; ++r) {
        int row = (r & 3) + 8 * (r >> 2) + 4 * lk;
        acc[nc][r] += Sb[row * 128 + nc * 32 + lc];
      }
  };
  __syncthreads();
  if (wave == 1) st(S0);
  if (wave == 3) st(S1);
  __syncthreads();
  if (wave == 0) ad(S0);
  if (wave == 2) ad(S1);
  __syncthreads();
  if (wave == 2) st(S0);
  __syncthreads();
  if (wave == 0) {
    ad(S0);   // full half-K sum in wave0 regs
    // store to hp slot (plain, coalesced-ish), then fence+count
    float* dst = hp + (size_t)(tile * 2 + kh) * 4096;
    #pragma unroll
    for (int nc = 0; nc < 4; ++nc)
      #pragma unroll
      for (int r = 0; r < 16; ++r) {
        int row = (r & 3) + 8 * (r >> 2) + 4 * lk;
        dst[row * 128 + nc * 32 + lc] = acc[nc][r];
      }
    __threadfence();
    if (l == 0) flag[0] = atomicAdd(&cnt_tile[tile], 1);
  }
  __syncthreads();
  if (flag[0] == 0) return;    // peer will finish this tile

  // ================= finisher: layer 2 + final dot ===========================
  // hr: row lc, dims wave*32 + lk*8 + [0,8) and +16 ; coherent atomic reads
  const float* hpA = hp + (size_t)(tile * 2 + 0) * 4096;
  const float* hpB = hp + (size_t)(tile * 2 + 1) * 4096;
  float hr0[8], hr1[8];
  {
    int col0 = wave * 32 + lk * 8;
    #pragma unroll
    for (int i = 0; i < 8; ++i) {
      hr0[i] = atomicAdd((float*)&hpA[lc * 128 + col0 + i], 0.f)
             + atomicAdd((float*)&hpB[lc * 128 + col0 + i], 0.f)
             + b1[col0 + i];
      hr1[i] = atomicAdd((float*)&hpA[lc * 128 + col0 + 16 + i], 0.f)
             + atomicAdd((float*)&hpB[lc * 128 + col0 + 16 + i], 0.f)
             + b1[col0 + 16 + i];
    }
  }

  floatx16 acc2[2] = {};
  auto loadB2 = [&](int s, uint4* cf) {
    int j = s >> 1, w = wave * 2 + (s & 1);
    const uint4* bp = B2 + (size_t)((w * 9 + j) * 2) * 64 + l;
    #pragma unroll
    for (int nc = 0; nc < 2; ++nc) cf[nc] = bp[nc * 64];
  };
  auto computeB2 = [&](int s, const uint4* cf) {
    int j = s >> 1;
    const float* hr = (s & 1) ? hr1 : hr0;
    float f[8];
    if (j == 0) {
      #pragma unroll
      for (int i = 0; i < 8; ++i)
        f[i] = __fdividef(hr[i], 1.f + __expf(-hr[i]));
    } else {
      float g = -2.f + (float)(j - 1) * (4.f / 7.f);
      #pragma unroll
      for (int i = 0; i < 8; ++i) {
        float z = (hr[i] - g) * 1.75f;
        f[i] = __expf(-z * z);
      }
    }
    short8 a;
    #pragma unroll
    for (int i = 0; i < 8; ++i) a[i] = (short)f2bf(f[i]);
    #pragma unroll
    for (int nc = 0; nc < 2; ++nc) {
      short8 bh = __builtin_bit_cast(short8, cf[nc]);
      acc2[nc] = __builtin_amdgcn_mfma_f32_32x32x16_bf16(a, bh, acc2[nc], 0, 0, 0);
    }
  };

  {
    uint4 cfE[2], cfO[2];
    loadB2(0, cfE);
    #pragma unroll 1
    for (int s = 0; s < 18; s += 2) {
      loadB2(s + 1, cfO);
      computeB2(s, cfE);
      if (s + 2 < 18) loadB2(s + 2, cfE);
      computeB2(s + 1, cfO);
    }
  }

  // ---- per-wave dot with final_w; cross-wave scalar sum ----
  const float* wf = finw + sid * 64;
  {
    float w0 = wf[lc], w1v = wf[32 + lc];
    float pz = 0.f;
    #pragma unroll
    for (int r = 0; r < 16; ++r) pz += acc2[0][r] * w0 + acc2[1][r] * w1v;
    #pragma unroll
    for (int off = 32; off > 0; off >>= 1) pz += __shfl_down(pz, off, 64);
    if (l == 0) redw[wave] = pz;
  }
  __syncthreads();

  // ---- tile partial + last-finisher-per-batch output ----
  if (wave == 0) {
    const int b    = m >> 5;
    const int slot = sid * 32 + (m & 31);
    float v = (l < 4) ? redw[l] : 0.f;
    v += 32.f * b2[l] * wf[l];               // bias over this tile's 32 rows
    #pragma unroll
    for (int off = 32; off > 0; off >>= 1) v += __shfl_down(v, off, 64);
    int old = 0;
    if (l == 0) {
      partial[b * 64 + slot] = v;
      __threadfence();
      old = atomicAdd(&cnt_batch[b], 1);
    }
    int bc = __shfl(old, 0, 64);
    if (bc == 63) {
      float pv = atomicAdd(&partial[b * 64 + l], 0.f);
      #pragma unroll
      for (int off = 32; off > 0; off >>= 1) pv += __shfl_down(pv, off, 64);
      if (l == 0) out[b] = finb[0] + pv * (1.0f / 1024.0f);
    }
  }
}

extern "C" void kernel_launch(void* const* d_in, const int* in_sizes, int n_in,
                              void* d_out, int out_size, void* d_ws, size_t ws_size,
                              hipStream_t stream)
{
  (void)in_sizes; (void)n_in; (void)out_size; (void)ws_size;
  const float* x    = (const float*)d_in[0];
  const float* y    = (const float*)d_in[1];
  const float* bw1x = (const float*)d_in[2];
  const float* bb1x = (const float*)d_in[3];
  const float* sw1x = (const float*)d_in[4];
  const float* sb1x = (const float*)d_in[5];
  const float* bw2x = (const float*)d_in[6];
  const float* bb2x = (const float*)d_in[7];
  const float* sw2x = (const float*)d_in[8];
  const float* sb2x = (const float*)d_in[9];
  const float* bw1y = (const float*)d_in[10];
  const float* bb1y = (const float*)d_in[11];
  const float* sw1y = (const float*)d_in[12];
  const float* sb1y = (const float*)d_in[13];
  const float* bw2y = (const float*)d_in[14];
  const float* bb2y = (const float*)d_in[15];
  const float* sw2y = (const float*)d_in[16];
  const float* sb2y = (const float*)d_in[17];
  const float* finw = (const float*)d_in[18];
  const float* finb = (const float*)d_in[19];

  char* ws = (char*)d_ws;
  uint4* B1fx = (uint4*)(ws);                       // 589824 B
  uint4* B1fy = (uint4*)(ws + 589824);
  uint4* B2fx = (uint4*)(ws + 1179648);             // 147456 B
  uint4* B2fy = (uint4*)(ws + 1327104);
  float* b1x  = (float*)(ws + 1474560);
  float* b1y  = b1x + 128;
  float* b2x  = b1y + 128;
  float* b2y  = b2x + 64;
  float* partial = b2y + 64;                        // 256 floats
  int*   cnts = (int*)(partial + 256);              // cnt_tile[256] + cnt_batch[4]
  int*   cnt_tile  = cnts;
  int*   cnt_batch = cnts + 256;
  float* hp   = (float*)(ws + 1572864);             // 2M floats = 8 MB

  int prep_total = 2 * 36864 + 2 * 9216 + 384 + 260;  // 92804
  int prep_blocks = (prep_total + 511) / 512;
  hipLaunchKernelGGL(prep_frags, dim3(prep_blocks), dim3(512), 0, stream,
                     bw1x, sw1x, bb1x, sb1x, bw2x, sw2x, bb2x, sb2x,
                     bw1y, sw1y, bb1y, sb1y, bw2y, sw2y, bb2y, sb2y,
                     B1fx, B1fy, B2fx, B2fy, b1x, b1y, b2x, b2y, cnts);

  hipLaunchKernelGGL(fused_kernel, dim3(512), dim3(256), 0, stream,
                     x, y, B1fx, B1fy, B2fx, B2fy, b1x, b1y, b2x, b2y,
                     finw, finb, hp, partial, cnt_tile, cnt_batch,
                     (float*)d_out);
}

// Round 13
// 36.385 us; speedup vs baseline: 2.8399x; 2.8399x over previous
//
#include <hip/hip_runtime.h>

typedef __attribute__((ext_vector_type(8))) short short8;
typedef __attribute__((ext_vector_type(16))) float floatx16;

// B1 frag layout (hi-only): per sid, q = (ds*9 + j)*4 + ncg  (ds<16, j<9, ncg<4)
//   uint4 slot = q*64 + l
// B2 frag layout (hi-only, N-split): per sid,
//   q2n = ((nh*8 + w)*5 + s)*2 + nc2   (nh<2, w<8, s<5, nc2<2); slot = q2n*64 + l
//   lane l, elem i: out o = nc2*32 + (l&31), plane p = s*2 + (l>>5),
//                   col d = nh*64 + w*8 + i;  p==9 -> 0 (pad plane)

__device__ __forceinline__ unsigned short f2bf(float f) {
  union { float f; unsigned u; } v; v.f = f;
  unsigned r = v.u + 0x7fffu + ((v.u >> 16) & 1u);
  return (unsigned short)(r >> 16);
}

__global__ __launch_bounds__(512) void prep_frags(
    const float* __restrict__ bw1x, const float* __restrict__ sw1x,
    const float* __restrict__ bb1x, const float* __restrict__ sb1x,
    const float* __restrict__ bw2x, const float* __restrict__ sw2x,
    const float* __restrict__ bb2x, const float* __restrict__ sb2x,
    const float* __restrict__ bw1y, const float* __restrict__ sw1y,
    const float* __restrict__ bb1y, const float* __restrict__ sb1y,
    const float* __restrict__ bw2y, const float* __restrict__ sw2y,
    const float* __restrict__ bb2y, const float* __restrict__ sb2y,
    uint4* __restrict__ B1fx, uint4* __restrict__ B1fy,
    uint4* __restrict__ B2fx, uint4* __restrict__ B2fy,
    float* __restrict__ b1x, float* __restrict__ b1y,
    float* __restrict__ b2x, float* __restrict__ b2y,
    int* __restrict__ cnts)
{
  int idx = blockIdx.x * 512 + threadIdx.x;
  if (idx < 2 * 36864) {                       // B1: 2 sids x 576 q x 64 l
    int sid = idx / 36864;
    int rem = idx - sid * 36864;
    int q = rem >> 6, l = rem & 63;
    int nc = q & 3, t9 = q >> 2;
    int j = t9 % 9, ds = t9 / 9;
    const float* bw = sid ? bw1y : bw1x;
    const float* sw = sid ? sw1y : sw1x;
    uint4* dst = sid ? B1fy : B1fx;
    int o = nc * 32 + (l & 31);
    int dbase = ds * 16 + (l >> 5) * 8;
    unsigned short eh[8];
    #pragma unroll
    for (int i = 0; i < 8; ++i) {
      int d = dbase + i;
      float wv = (j == 0) ? bw[o * 256 + d] : sw[o * 2048 + d * 8 + (j - 1)];
      eh[i] = f2bf(wv);
    }
    uint4 oh;
    oh.x = (unsigned)eh[0] | ((unsigned)eh[1] << 16);
    oh.y = (unsigned)eh[2] | ((unsigned)eh[3] << 16);
    oh.z = (unsigned)eh[4] | ((unsigned)eh[5] << 16);
    oh.w = (unsigned)eh[6] | ((unsigned)eh[7] << 16);
    dst[q * 64 + l] = oh;
  } else if (idx < 2 * 36864 + 2 * 10240) {    // B2: 2 sids x 160 q2n x 64 l
    int i2 = idx - 2 * 36864;
    int sid = i2 / 10240;
    int rem = i2 - sid * 10240;
    int q2n = rem >> 6, l = rem & 63;
    int nc2 = q2n & 1, t5 = q2n >> 1;
    int s = t5 % 5, wn = t5 / 5;
    int nh = wn >> 3, w = wn & 7;
    const float* bw = sid ? bw2y : bw2x;
    const float* sw = sid ? sw2y : sw2x;
    uint4* dst = sid ? B2fy : B2fx;
    int o = nc2 * 32 + (l & 31);
    int p = s * 2 + (l >> 5);
    int dbase = nh * 64 + w * 8;
    unsigned short eh[8];
    #pragma unroll
    for (int i = 0; i < 8; ++i) {
      int d = dbase + i;
      float wv;
      if (p == 0)       wv = bw[o * 128 + d];
      else if (p < 9)   wv = sw[o * 1024 + d * 8 + (p - 1)];
      else              wv = 0.f;
      eh[i] = f2bf(wv);
    }
    uint4 oh;
    oh.x = (unsigned)eh[0] | ((unsigned)eh[1] << 16);
    oh.y = (unsigned)eh[2] | ((unsigned)eh[3] << 16);
    oh.z = (unsigned)eh[4] | ((unsigned)eh[5] << 16);
    oh.w = (unsigned)eh[6] | ((unsigned)eh[7] << 16);
    dst[q2n * 64 + l] = oh;
  } else {
    int i2 = idx - (2 * 36864 + 2 * 10240);
    if (i2 < 128)      b1x[i2]       = bb1x[i2]       + sb1x[i2];
    else if (i2 < 256) b1y[i2 - 128] = bb1y[i2 - 128] + sb1y[i2 - 128];
    else if (i2 < 320) b2x[i2 - 256] = bb2x[i2 - 256] + sb2x[i2 - 256];
    else if (i2 < 384) b2y[i2 - 320] = bb2y[i2 - 320] + sb2y[i2 - 320];
    else if (i2 < 388) cnts[i2 - 384] = 0;
  }
}

// ---------- fused: block = (sid, 64-row tile mt, N-half nh); 512 thr, 8 waves
__global__ __launch_bounds__(512, 2) void fused_kernel(
    const float* __restrict__ Xx, const float* __restrict__ Xy,
    const uint4* __restrict__ B1fx, const uint4* __restrict__ B1fy,
    const uint4* __restrict__ B2fx, const uint4* __restrict__ B2fy,
    const float* __restrict__ b1x_, const float* __restrict__ b1y_,
    const float* __restrict__ b2x_, const float* __restrict__ b2y_,
    const float* __restrict__ finw, const float* __restrict__ finb,
    float* __restrict__ partial, int* __restrict__ cnt_batch,
    float* __restrict__ out)
{
  __shared__ __align__(16) char smem[50240];
  float* S0   = (float*)smem;               // 16 KB  (64x64 tree buf)
  float* S1   = (float*)(smem + 16384);     // 16 KB
  float* h1s  = (float*)(smem + 32768);     // 64*68 floats = 17408 B
  float* redw = (float*)(smem + 50176);     // 8 floats

  const int t    = threadIdx.x;
  const int bid  = blockIdx.x;
  const int sid  = bid >> 7;
  const int rem  = bid & 127;
  const int mt   = rem >> 1;       // 64-row tile
  const int nh   = rem & 1;        // N-half
  const int wave = t >> 6;
  const int l    = t & 63;
  const int lc   = l & 31;
  const int lk   = l >> 5;

  const float* X  = sid ? Xy : Xx;
  const uint4* B1 = sid ? B1fy : B1fx;
  const uint4* B2 = sid ? B2fy : B2fx;
  const float* b1 = sid ? b1y_ : b1x_;
  const float* b2 = sid ? b2y_ : b2x_;

  // ---- per-lane x data, direct from global (L3-resident):
  //      rows lc, lc+32 of tile; dims wave*32 + {0,16} + lk*8 + [0,8)
  float xr[2][2][8];
  {
    const float* xb = X + (size_t)(mt * 64) * 256 + wave * 32 + lk * 8;
    #pragma unroll
    for (int rg = 0; rg < 2; ++rg) {
      const float* rp = xb + (size_t)(lc + rg * 32) * 256;
      float4 a0 = *(const float4*)(rp);
      float4 a1 = *(const float4*)(rp + 4);
      float4 c0 = *(const float4*)(rp + 16);
      float4 c1 = *(const float4*)(rp + 20);
      xr[rg][0][0]=a0.x; xr[rg][0][1]=a0.y; xr[rg][0][2]=a0.z; xr[rg][0][3]=a0.w;
      xr[rg][0][4]=a1.x; xr[rg][0][5]=a1.y; xr[rg][0][6]=a1.z; xr[rg][0][7]=a1.w;
      xr[rg][1][0]=c0.x; xr[rg][1][1]=c0.y; xr[rg][1][2]=c0.z; xr[rg][1][3]=c0.w;
      xr[rg][1][4]=c1.x; xr[rg][1][5]=c1.y; xr[rg][1][6]=c1.z; xr[rg][1][7]=c1.w;
    }
  }

  // ================= layer 1: 18 steps (9 j x 2 ds), full K, N-half ==========
  floatx16 acc[2][2] = {};

  auto loadB1 = [&](int s, uint4* bf) {
    int j = s >> 1, ds = wave * 2 + (s & 1);
    const uint4* bp = B1 + (size_t)((ds * 9 + j) * 4 + nh * 2) * 64 + l;
    bf[0] = bp[0];
    bf[1] = bp[64];
  };
  auto computeB1 = [&](int s, const uint4* bf) {
    int j = s >> 1, dh = s & 1;
    short8 a[2];
    #pragma unroll
    for (int rg = 0; rg < 2; ++rg) {
      float f[8];
      if (j == 0) {
        #pragma unroll
        for (int i = 0; i < 8; ++i) {
          float xv = xr[rg][dh][i];
          f[i] = __fdividef(xv, 1.f + __expf(-xv));
        }
      } else {
        float g = -2.f + (float)(j - 1) * (4.f / 7.f);
        #pragma unroll
        for (int i = 0; i < 8; ++i) {
          float z = (xr[rg][dh][i] - g) * 1.75f;
          f[i] = __expf(-z * z);
        }
      }
      #pragma unroll
      for (int i = 0; i < 8; ++i) a[rg][i] = (short)f2bf(f[i]);
    }
    #pragma unroll
    for (int rg = 0; rg < 2; ++rg)
      #pragma unroll
      for (int nc = 0; nc < 2; ++nc) {
        short8 bh = __builtin_bit_cast(short8, bf[nc]);
        acc[rg][nc] = __builtin_amdgcn_mfma_f32_32x32x16_bf16(a[rg], bh, acc[rg][nc], 0, 0, 0);
      }
  };

  {
    uint4 bfE[2], bfO[2];
    loadB1(0, bfE);
    #pragma unroll 1
    for (int s = 0; s < 18; s += 2) {
      loadB1(s + 1, bfO);
      computeB1(s, bfE);
      if (s + 2 < 18) loadB1(s + 2, bfE);
      computeB1(s + 1, bfO);
    }
  }

  // ---- cross-wave K reduction: race-free 2-buffer tree (64x64 tile) ----
  auto st = [&](float* Sb) {
    #pragma unroll
    for (int rg = 0; rg < 2; ++rg)
      #pragma unroll
      for (int nc = 0; nc < 2; ++nc)
        #pragma unroll
        for (int r = 0; r < 16; ++r) {
          int row = rg * 32 + (r & 3) + 8 * (r >> 2) + 4 * lk;
          Sb[row * 64 + nc * 32 + lc] = acc[rg][nc][r];
        }
  };
  auto ad = [&](const float* Sb) {
    #pragma unroll
    for (int rg = 0; rg < 2; ++rg)
      #pragma unroll
      for (int nc = 0; nc < 2; ++nc)
        #pragma unroll
        for (int r = 0; r < 16; ++r) {
          int row = rg * 32 + (r & 3) + 8 * (r >> 2) + 4 * lk;
          acc[rg][nc][r] += Sb[row * 64 + nc * 32 + lc];
        }
  };
  __syncthreads();
  if (wave == 1) st(S0);
  if (wave == 3) st(S1);
  __syncthreads();
  if (wave == 0) ad(S0);
  if (wave == 2) ad(S1);
  __syncthreads();
  if (wave == 5) st(S0);
  if (wave == 7) st(S1);
  __syncthreads();
  if (wave == 4) ad(S0);
  if (wave == 6) ad(S1);
  __syncthreads();
  if (wave == 2) st(S0);
  if (wave == 6) st(S1);
  __syncthreads();
  if (wave == 0) ad(S0);
  if (wave == 4) ad(S1);
  __syncthreads();
  if (wave == 4) st(S0);
  __syncthreads();
  if (wave == 0) {
    ad(S0);
    #pragma unroll
    for (int rg = 0; rg < 2; ++rg)
      #pragma unroll
      for (int nc = 0; nc < 2; ++nc)
        #pragma unroll
        for (int r = 0; r < 16; ++r) {
          int row = rg * 32 + (r & 3) + 8 * (r >> 2) + 4 * lk;
          int colL = nc * 32 + lc;
          h1s[row * 68 + colL] = acc[rg][nc][r] + b1[nh * 64 + colL];
        }
  }
  __syncthreads();

  // ================= layer 2: K-slice = this block's 64 cols x 9 planes ======
  // wave owns cols w*8..+8 (local); 5 steps of K=16 (plane p = s*2+lk, p=9 pad)
  float hr[2][8];
  {
    #pragma unroll
    for (int rg = 0; rg < 2; ++rg) {
      const float* rp = h1s + (size_t)(lc + rg * 32) * 68 + wave * 8;
      float4 v0 = *(const float4*)(rp);
      float4 v1 = *(const float4*)(rp + 4);
      hr[rg][0]=v0.x; hr[rg][1]=v0.y; hr[rg][2]=v0.z; hr[rg][3]=v0.w;
      hr[rg][4]=v1.x; hr[rg][5]=v1.y; hr[rg][6]=v1.z; hr[rg][7]=v1.w;
    }
  }

  floatx16 acc2[2][2] = {};
  auto loadB2 = [&](int s, uint4* cf) {
    const uint4* bp = B2 + (size_t)((((nh * 8 + wave) * 5 + s) * 2)) * 64 + l;
    cf[0] = bp[0];
    cf[1] = bp[64];
  };
  auto computeB2 = [&](int s, const uint4* cf) {
    int p = s * 2 + lk;                    // lane's plane
    short8 a[2];
    #pragma unroll
    for (int rg = 0; rg < 2; ++rg) {
      float f[8];
      if (p == 0) {
        #pragma unroll
        for (int i = 0; i < 8; ++i) {
          float hv = hr[rg][i];
          f[i] = __fdividef(hv, 1.f + __expf(-hv));
        }
      } else if (p == 9) {
        #pragma unroll
        for (int i = 0; i < 8; ++i) f[i] = 0.f;
      } else {
        float g = -2.f + (float)(p - 1) * (4.f / 7.f);
        #pragma unroll
        for (int i = 0; i < 8; ++i) {
          float z = (hr[rg][i] - g) * 1.75f;
          f[i] = __expf(-z * z);
        }
      }
      #pragma unroll
      for (int i = 0; i < 8; ++i) a[rg][i] = (short)f2bf(f[i]);
    }
    #pragma unroll
    for (int rg = 0; rg < 2; ++rg)
      #pragma unroll
      for (int nc2 = 0; nc2 < 2; ++nc2) {
        short8 bh = __builtin_bit_cast(short8, cf[nc2]);
        acc2[rg][nc2] = __builtin_amdgcn_mfma_f32_32x32x16_bf16(a[rg], bh, acc2[rg][nc2], 0, 0, 0);
      }
  };

  {
    uint4 cfE[2], cfO[2];
    loadB2(0, cfE);
    loadB2(1, cfO); computeB2(0, cfE); loadB2(2, cfE); computeB2(1, cfO);
    loadB2(3, cfO); computeB2(2, cfE); loadB2(4, cfE); computeB2(3, cfO);
    computeB2(4, cfE);
  }

  // ---- per-wave dot with final_w; cross-wave scalar sum ----
  const float* wf = finw + sid * 64;
  {
    float w0 = wf[lc], w1v = wf[32 + lc];
    float pz = 0.f;
    #pragma unroll
    for (int rg = 0; rg < 2; ++rg)
      #pragma unroll
      for (int r = 0; r < 16; ++r)
        pz += acc2[rg][0][r] * w0 + acc2[rg][1][r] * w1v;
    #pragma unroll
    for (int off = 32; off > 0; off >>= 1) pz += __shfl_down(pz, off, 64);
    if (l == 0) redw[wave] = pz;
  }
  __syncthreads();

  // ---- block partial + last-block-per-batch finish ----
  if (wave == 0) {
    const int b    = rem >> 5;               // batch (32 blocks per batch per sid? 32 blocks: 16 tiles x 2 nh)
    const int slot = sid * 32 + (rem & 31);  // 64 slots per batch
    float v = (l < 8) ? redw[l] : 0.f;
    if (nh == 0) v += 64.f * b2[l] * wf[l];  // bias once per (row,o): 64 rows
    #pragma unroll
    for (int off = 32; off > 0; off >>= 1) v += __shfl_down(v, off, 64);
    int old = 0;
    if (l == 0) {
      partial[b * 64 + slot] = v;
      __threadfence();
      old = atomicAdd(&cnt_batch[b], 1);
    }
    int bc = __shfl(old, 0, 64);
    if (bc == 63) {                          // last block of this batch
      float pv = atomicAdd(&partial[b * 64 + l], 0.f);  // coherent read
      #pragma unroll
      for (int off = 32; off > 0; off >>= 1) pv += __shfl_down(pv, off, 64);
      if (l == 0) out[b] = finb[0] + pv * (1.0f / 1024.0f);
    }
  }
}

extern "C" void kernel_launch(void* const* d_in, const int* in_sizes, int n_in,
                              void* d_out, int out_size, void* d_ws, size_t ws_size,
                              hipStream_t stream)
{
  (void)in_sizes; (void)n_in; (void)out_size; (void)ws_size;
  const float* x    = (const float*)d_in[0];
  const float* y    = (const float*)d_in[1];
  const float* bw1x = (const float*)d_in[2];
  const float* bb1x = (const float*)d_in[3];
  const float* sw1x = (const float*)d_in[4];
  const float* sb1x = (const float*)d_in[5];
  const float* bw2x = (const float*)d_in[6];
  const float* bb2x = (const float*)d_in[7];
  const float* sw2x = (const float*)d_in[8];
  const float* sb2x = (const float*)d_in[9];
  const float* bw1y = (const float*)d_in[10];
  const float* bb1y = (const float*)d_in[11];
  const float* sw1y = (const float*)d_in[12];
  const float* sb1y = (const float*)d_in[13];
  const float* bw2y = (const float*)d_in[14];
  const float* bb2y = (const float*)d_in[15];
  const float* sw2y = (const float*)d_in[16];
  const float* sb2y = (const float*)d_in[17];
  const float* finw = (const float*)d_in[18];
  const float* finb = (const float*)d_in[19];

  char* ws = (char*)d_ws;
  uint4* B1fx = (uint4*)(ws);                       // 589824 B
  uint4* B1fy = (uint4*)(ws + 589824);
  uint4* B2fx = (uint4*)(ws + 1179648);             // 163840 B
  uint4* B2fy = (uint4*)(ws + 1343488);
  float* b1x  = (float*)(ws + 1507328);
  float* b1y  = b1x + 128;
  float* b2x  = b1y + 128;
  float* b2y  = b2x + 64;
  float* partial = b2y + 64;                        // 256 floats
  int*   cnt_batch = (int*)(partial + 256);         // 4 ints

  int prep_total = 2 * 36864 + 2 * 10240 + 388;     // 94596
  int prep_blocks = (prep_total + 511) / 512;
  hipLaunchKernelGGL(prep_frags, dim3(prep_blocks), dim3(512), 0, stream,
                     bw1x, sw1x, bb1x, sb1x, bw2x, sw2x, bb2x, sb2x,
                     bw1y, sw1y, bb1y, sb1y, bw2y, sw2y, bb2y, sb2y,
                     B1fx, B1fy, B2fx, B2fy, b1x, b1y, b2x, b2y, cnt_batch);

  hipLaunchKernelGGL(fused_kernel, dim3(256), dim3(512), 0, stream,
                     x, y, B1fx, B1fy, B2fx, B2fy, b1x, b1y, b2x, b2y,
                     finw, finb, partial, cnt_batch, (float*)d_out);
}

// Round 14
// 31.094 us; speedup vs baseline: 3.3231x; 1.1702x over previous
//
#include <hip/hip_runtime.h>

typedef __attribute__((ext_vector_type(8))) short short8;
typedef __attribute__((ext_vector_type(8))) float floatx8;
typedef __attribute__((ext_vector_type(8))) __bf16 bf16x8;
typedef __attribute__((ext_vector_type(16))) float floatx16;

// B1 frag layout (hi-only): per sid, q = (ds*9 + j)*4 + nc  (ds<16, j<9, nc<4)
//   uint4 slot = q*64 + l   (l = lane)
// B2 frag layout: per sid, q2 = (w*9 + j)*2 + nc (w<8, nc<2); slot = q2*64 + l

__device__ __forceinline__ unsigned short f2bf(float f) {
  union { float f; unsigned u; } v; v.f = f;
  unsigned r = v.u + 0x7fffu + ((v.u >> 16) & 1u);
  return (unsigned short)(r >> 16);
}

__global__ __launch_bounds__(512) void prep_frags(
    const float* __restrict__ bw1x, const float* __restrict__ sw1x,
    const float* __restrict__ bb1x, const float* __restrict__ sb1x,
    const float* __restrict__ bw2x, const float* __restrict__ sw2x,
    const float* __restrict__ bb2x, const float* __restrict__ sb2x,
    const float* __restrict__ bw1y, const float* __restrict__ sw1y,
    const float* __restrict__ bb1y, const float* __restrict__ sb1y,
    const float* __restrict__ bw2y, const float* __restrict__ sw2y,
    const float* __restrict__ bb2y, const float* __restrict__ sb2y,
    uint4* __restrict__ B1fx, uint4* __restrict__ B1fy,
    uint4* __restrict__ B2fx, uint4* __restrict__ B2fy,
    float* __restrict__ b1x, float* __restrict__ b1y,
    float* __restrict__ b2x, float* __restrict__ b2y,
    int* __restrict__ cnt)
{
  int idx = blockIdx.x * 512 + threadIdx.x;
  if (idx < 2 * 36864) {                       // B1: 2 sids x 576 q x 64 l
    int sid = idx / 36864;
    int rem = idx - sid * 36864;
    int q = rem >> 6, l = rem & 63;
    int nc = q & 3, t9 = q >> 2;
    int j = t9 % 9, ds = t9 / 9;
    const float* bw = sid ? bw1y : bw1x;
    const float* sw = sid ? sw1y : sw1x;
    uint4* dst = sid ? B1fy : B1fx;
    int o = nc * 32 + (l & 31);
    int dbase = ds * 16 + (l >> 5) * 8;
    unsigned short eh[8];
    #pragma unroll
    for (int i = 0; i < 8; ++i) {
      int d = dbase + i;
      float wv = (j == 0) ? bw[o * 256 + d] : sw[o * 2048 + d * 8 + (j - 1)];
      eh[i] = f2bf(wv);
    }
    uint4 oh;
    oh.x = (unsigned)eh[0] | ((unsigned)eh[1] << 16);
    oh.y = (unsigned)eh[2] | ((unsigned)eh[3] << 16);
    oh.z = (unsigned)eh[4] | ((unsigned)eh[5] << 16);
    oh.w = (unsigned)eh[6] | ((unsigned)eh[7] << 16);
    dst[q * 64 + l] = oh;
  } else if (idx < 2 * 36864 + 2 * 9216) {     // B2: 2 sids x 144 q2 x 64 l
    int i2 = idx - 2 * 36864;
    int sid = i2 / 9216;
    int rem = i2 - sid * 9216;
    int q2 = rem >> 6, l = rem & 63;
    int nc = q2 & 1, t9 = q2 >> 1;
    int j = t9 % 9, w = t9 / 9;
    const float* bw = sid ? bw2y : bw2x;
    const float* sw = sid ? sw2y : sw2x;
    uint4* dst = sid ? B2fy : B2fx;
    int o = nc * 32 + (l & 31);
    int dbase = w * 16 + (l >> 5) * 8;
    unsigned short eh[8];
    #pragma unroll
    for (int i = 0; i < 8; ++i) {
      int d = dbase + i;
      float wv = (j == 0) ? bw[o * 128 + d] : sw[o * 1024 + d * 8 + (j - 1)];
      eh[i] = f2bf(wv);
    }
    uint4 oh;
    oh.x = (unsigned)eh[0] | ((unsigned)eh[1] << 16);
    oh.y = (unsigned)eh[2] | ((unsigned)eh[3] << 16);
    oh.z = (unsigned)eh[4] | ((unsigned)eh[5] << 16);
    oh.w = (unsigned)eh[6] | ((unsigned)eh[7] << 16);
    dst[q2 * 64 + l] = oh;
  } else {
    int i2 = idx - (2 * 36864 + 2 * 9216);
    if (i2 < 128)      b1x[i2]       = bb1x[i2]       + sb1x[i2];
    else if (i2 < 256) b1y[i2 - 128] = bb1y[i2 - 128] + sb1y[i2 - 128];
    else if (i2 < 320) b2x[i2 - 256] = bb2x[i2 - 256] + sb2x[i2 - 256];
    else if (i2 < 384) b2y[i2 - 320] = bb2y[i2 - 320] + sb2y[i2 - 320];
    else if (i2 < 388) cnt[i2 - 384] = 0;
  }
}

// ---------- fused: both layers + last-block finish; block = (sid, 32-row tile m)
__global__ __launch_bounds__(512, 2) void fused_kernel(
    const float* __restrict__ Xx, const float* __restrict__ Xy,
    const uint4* __restrict__ B1fx, const uint4* __restrict__ B1fy,
    const uint4* __restrict__ B2fx, const uint4* __restrict__ B2fy,
    const float* __restrict__ b1x_, const float* __restrict__ b1y_,
    const float* __restrict__ b2x_, const float* __restrict__ b2y_,
    const float* __restrict__ finw, const float* __restrict__ finb,
    float* __restrict__ partial, int* __restrict__ cnt,
    float* __restrict__ out)
{
  __shared__ __align__(16) char smem[51232];
  float* xsh  = (float*)smem;               // 32*264 floats = 33792 B
  float* S0   = (float*)smem;               // 16 KB (alias; used after xr read)
  float* S1   = (float*)(smem + 16384);     // 16 KB
  float* h1s  = (float*)(smem + 33792);     // 32*136 floats = 17408 B
  float* redw = (float*)(smem + 51200);     // 8 floats

  const int t    = threadIdx.x;
  const int bid  = blockIdx.x;
  const int sid  = bid >> 7;
  const int m    = bid & 127;
  const int wave = t >> 6;
  const int l    = t & 63;
  const int lc   = l & 31;
  const int lk   = l >> 5;

  const float* X  = sid ? Xy : Xx;
  const uint4* B1 = sid ? B1fy : B1fx;
  const uint4* B2 = sid ? B2fy : B2fx;
  const float* b1 = sid ? b1y_ : b1x_;
  const float* b2 = sid ? b2y_ : b2x_;

  // ---- stage x tile: 32 rows x 256, coalesced ----
  {
    int row = t >> 4, col = (t & 15) * 16;
    const float* src = X + (size_t)(m * 32 + row) * 256 + col;
    #pragma unroll
    for (int q = 0; q < 4; ++q)
      *(float4*)(xsh + row * 264 + col + q * 4) = *(const float4*)(src + q * 4);
  }
  __syncthreads();

  // per-lane A data: row lc, dims for ds0 = 2*wave and ds1 = 2*wave+1
  float xr0[8], xr1[8];
  {
    int cb = wave * 32 + lk * 8;
    float4 v0 = *(const float4*)(xsh + lc * 264 + cb);
    float4 v1 = *(const float4*)(xsh + lc * 264 + cb + 4);
    float4 u0 = *(const float4*)(xsh + lc * 264 + cb + 16);
    float4 u1 = *(const float4*)(xsh + lc * 264 + cb + 20);
    xr0[0]=v0.x; xr0[1]=v0.y; xr0[2]=v0.z; xr0[3]=v0.w;
    xr0[4]=v1.x; xr0[5]=v1.y; xr0[6]=v1.z; xr0[7]=v1.w;
    xr1[0]=u0.x; xr1[1]=u0.y; xr1[2]=u0.z; xr1[3]=u0.w;
    xr1[4]=u1.x; xr1[5]=u1.y; xr1[6]=u1.z; xr1[7]=u1.w;
  }
  __syncthreads();   // xsh dead; S0/S1 free

  // ================= layer 1: 18 steps (9 j x 2 ds), 1-step lookahead ========
  floatx16 acc[4] = {};

  auto loadB1 = [&](int s, uint4* bf) {
    int j = s >> 1, ds = wave * 2 + (s & 1);
    const uint4* bp = B1 + (size_t)((ds * 9 + j) * 4) * 64 + l;
    #pragma unroll
    for (int nc = 0; nc < 4; ++nc) bf[nc] = bp[nc * 64];
  };
  auto computeB1 = [&](int s, const uint4* bf) {
    int j = s >> 1;
    const float* xr = (s & 1) ? xr1 : xr0;
    floatx8 f;
    if (j == 0) {
      #pragma unroll
      for (int i = 0; i < 8; ++i)
        f[i] = __fdividef(xr[i], 1.f + __expf(-xr[i]));
    } else {
      float g = -2.f + (float)(j - 1) * (4.f / 7.f);
      #pragma unroll
      for (int i = 0; i < 8; ++i) {
        float z = (xr[i] - g) * 1.75f;
        f[i] = __expf(-z * z);
      }
    }
    short8 a = __builtin_bit_cast(short8, __builtin_convertvector(f, bf16x8));
    #pragma unroll
    for (int nc = 0; nc < 4; ++nc) {
      short8 bh = __builtin_bit_cast(short8, bf[nc]);
      acc[nc] = __builtin_amdgcn_mfma_f32_32x32x16_bf16(a, bh, acc[nc], 0, 0, 0);
    }
  };

  {
    uint4 bfE[4], bfO[4];
    loadB1(0, bfE);
    #pragma unroll 1
    for (int s = 0; s < 18; s += 2) {
      loadB1(s + 1, bfO);
      computeB1(s, bfE);
      if (s + 2 < 18) loadB1(s + 2, bfE);
      computeB1(s + 1, bfO);
    }
  }

  // ---- cross-wave K reduction: race-free 2-buffer tree (32x128 tile) ----
  auto st = [&](float* Sb) {
    #pragma unroll
    for (int nc = 0; nc < 4; ++nc)
      #pragma unroll
      for (int r = 0; r < 16; ++r) {
        int row = (r & 3) + 8 * (r >> 2) + 4 * lk;
        Sb[row * 128 + nc * 32 + lc] = acc[nc][r];
      }
  };
  auto ad = [&](const float* Sb) {
    #pragma unroll
    for (int nc = 0; nc < 4; ++nc)
      #pragma unroll
      for (int r = 0; r < 16; ++r) {
        int row = (r & 3) + 8 * (r >> 2) + 4 * lk;
        acc[nc][r] += Sb[row * 128 + nc * 32 + lc];
      }
  };
  __syncthreads();
  if (wave == 1) st(S0);
  if (wave == 3) st(S1);
  __syncthreads();
  if (wave == 0) ad(S0);
  if (wave == 2) ad(S1);
  __syncthreads();
  if (wave == 5) st(S0);
  if (wave == 7) st(S1);
  __syncthreads();
  if (wave == 4) ad(S0);
  if (wave == 6) ad(S1);
  __syncthreads();
  if (wave == 2) st(S0);
  if (wave == 6) st(S1);
  __syncthreads();
  if (wave == 0) ad(S0);
  if (wave == 4) ad(S1);
  __syncthreads();
  if (wave == 4) st(S0);
  __syncthreads();
  if (wave == 0) {
    ad(S0);
    #pragma unroll
    for (int nc = 0; nc < 4; ++nc)
      #pragma unroll
      for (int r = 0; r < 16; ++r) {
        int row = (r & 3) + 8 * (r >> 2) + 4 * lk;
        int col = nc * 32 + lc;
        h1s[row * 136 + col] = acc[nc][r] + b1[col];
      }
  }
  __syncthreads();

  // ================= layer 2: 9 steps, 1-step lookahead =================
  floatx16 acc2[2] = {};

  auto loadB2 = [&](int s, uint4* cf) {
    const uint4* bp = B2 + (size_t)((wave * 9 + s) * 2) * 64 + l;
    #pragma unroll
    for (int nc = 0; nc < 2; ++nc) cf[nc] = bp[nc * 64];
  };

  uint4 cfE[2], cfO[2];
  loadB2(0, cfE);              // issue before h1 read; independent

  float hr[8];
  {
    int cb = wave * 16 + lk * 8;
    float4 v0 = *(const float4*)(h1s + lc * 136 + cb);
    float4 v1 = *(const float4*)(h1s + lc * 136 + cb + 4);
    hr[0]=v0.x; hr[1]=v0.y; hr[2]=v0.z; hr[3]=v0.w;
    hr[4]=v1.x; hr[5]=v1.y; hr[6]=v1.z; hr[7]=v1.w;
  }

  auto computeB2 = [&](int s, const uint4* cf) {
    floatx8 f;
    if (s == 0) {
      #pragma unroll
      for (int i = 0; i < 8; ++i)
        f[i] = __fdividef(hr[i], 1.f + __expf(-hr[i]));
    } else {
      float g = -2.f + (float)(s - 1) * (4.f / 7.f);
      #pragma unroll
      for (int i = 0; i < 8; ++i) {
        float z = (hr[i] - g) * 1.75f;
        f[i] = __expf(-z * z);
      }
    }
    short8 a = __builtin_bit_cast(short8, __builtin_convertvector(f, bf16x8));
    #pragma unroll
    for (int nc = 0; nc < 2; ++nc) {
      short8 bh = __builtin_bit_cast(short8, cf[nc]);
      acc2[nc] = __builtin_amdgcn_mfma_f32_32x32x16_bf16(a, bh, acc2[nc], 0, 0, 0);
    }
  };

  #pragma unroll 1
  for (int s = 0; s < 8; s += 2) {
    loadB2(s + 1, cfO);
    computeB2(s, cfE);
    loadB2(s + 2, cfE);
    computeB2(s + 1, cfO);
  }
  computeB2(8, cfE);

  // ---- per-wave dot with final_w; cross-wave scalar sum ----
  const float* wf = finw + sid * 64;
  {
    float w0 = wf[lc], w1v = wf[32 + lc];
    float pz = 0.f;
    #pragma unroll
    for (int r = 0; r < 16; ++r) pz += acc2[0][r] * w0 + acc2[1][r] * w1v;
    #pragma unroll
    for (int off = 32; off > 0; off >>= 1) pz += __shfl_down(pz, off, 64);
    if (l == 0) redw[wave] = pz;
  }
  __syncthreads();

  // ---- block partial + last-block-per-batch finish ----
  if (wave == 0) {
    const int b    = m >> 5;                 // batch
    const int slot = sid * 32 + (m & 31);    // 64 slots per batch
    float v = (l < 8) ? redw[l] : 0.f;
    v += 32.f * b2[l] * wf[l];               // bias term over this block's 32 rows
    #pragma unroll
    for (int off = 32; off > 0; off >>= 1) v += __shfl_down(v, off, 64);
    int old = 0;
    if (l == 0) {
      partial[b * 64 + slot] = v;
      __threadfence();
      old = atomicAdd(&cnt[b], 1);
    }
    int bc = __shfl(old, 0, 64);
    if (bc == 63) {                          // last block of this batch
      float pv = atomicAdd(&partial[b * 64 + l], 0.f);  // coherent read
      #pragma unroll
      for (int off = 32; off > 0; off >>= 1) pv += __shfl_down(pv, off, 64);
      if (l == 0) out[b] = finb[0] + pv * (1.0f / 1024.0f);
    }
  }
}

extern "C" void kernel_launch(void* const* d_in, const int* in_sizes, int n_in,
                              void* d_out, int out_size, void* d_ws, size_t ws_size,
                              hipStream_t stream)
{
  (void)in_sizes; (void)n_in; (void)out_size; (void)ws_size;
  const float* x    = (const float*)d_in[0];
  const float* y    = (const float*)d_in[1];
  const float* bw1x = (const float*)d_in[2];
  const float* bb1x = (const float*)d_in[3];
  const float* sw1x = (const float*)d_in[4];
  const float* sb1x = (const float*)d_in[5];
  const float* bw2x = (const float*)d_in[6];
  const float* bb2x = (const float*)d_in[7];
  const float* sw2x = (const float*)d_in[8];
  const float* sb2x = (const float*)d_in[9];
  const float* bw1y = (const float*)d_in[10];
  const float* bb1y = (const float*)d_in[11];
  const float* sw1y = (const float*)d_in[12];
  const float* sb1y = (const float*)d_in[13];
  const float* bw2y = (const float*)d_in[14];
  const float* bb2y = (const float*)d_in[15];
  const float* sw2y = (const float*)d_in[16];
  const float* sb2y = (const float*)d_in[17];
  const float* finw = (const float*)d_in[18];
  const float* finb = (const float*)d_in[19];

  char* ws = (char*)d_ws;
  uint4* B1fx = (uint4*)(ws);                       // 589824 B
  uint4* B1fy = (uint4*)(ws + 589824);
  uint4* B2fx = (uint4*)(ws + 1179648);             // 147456 B
  uint4* B2fy = (uint4*)(ws + 1327104);
  float* b1x  = (float*)(ws + 1474560);
  float* b1y  = b1x + 128;
  float* b2x  = b1y + 128;
  float* b2y  = b2x + 64;
  float* partial = b2y + 64;                        // 256 floats
  int*   cnt  = (int*)(partial + 256);              // 4 ints

  int prep_total = 2 * 36864 + 2 * 9216 + 388;      // 92548
  int prep_blocks = (prep_total + 511) / 512;
  hipLaunchKernelGGL(prep_frags, dim3(prep_blocks), dim3(512), 0, stream,
                     bw1x, sw1x, bb1x, sb1x, bw2x, sw2x, bb2x, sb2x,
                     bw1y, sw1y, bb1y, sb1y, bw2y, sw2y, bb2y, sb2y,
                     B1fx, B1fy, B2fx, B2fy, b1x, b1y, b2x, b2y, cnt);

  hipLaunchKernelGGL(fused_kernel, dim3(256), dim3(512), 0, stream,
                     x, y, B1fx, B1fy, B2fx, B2fy, b1x, b1y, b2x, b2y,
                     finw, finb, partial, cnt, (float*)d_out);
}

// Round 16
// 30.604 us; speedup vs baseline: 3.3763x; 1.0160x over previous
//
#include <hip/hip_runtime.h>

typedef __attribute__((ext_vector_type(8))) short short8;
typedef __attribute__((ext_vector_type(8))) float floatx8;
typedef __attribute__((ext_vector_type(8))) __bf16 bf16x8;
typedef __attribute__((ext_vector_type(16))) float floatx16;

// B1 frag layout (hi-only): per sid, q = (ds*9 + j)*4 + nc  (ds<16, j<9, nc<4)
//   uint4 slot = q*64 + l   (l = lane)
// B2 frag layout: per sid, q2 = (w*9 + j)*2 + nc (w<8, nc<2); slot = q2*64 + l

__device__ __forceinline__ unsigned short f2bf(float f) {
  union { float f; unsigned u; } v; v.f = f;
  unsigned r = v.u + 0x7fffu + ((v.u >> 16) & 1u);
  return (unsigned short)(r >> 16);
}

// coalesced prep: block = one (ds, nc) chunk; LDS transpose; 1KB coalesced writes
#define STP 33   // stage row stride (ushorts)

__global__ __launch_bounds__(256) void prep_frags(
    const float* __restrict__ bw1x, const float* __restrict__ sw1x,
    const float* __restrict__ bb1x, const float* __restrict__ sb1x,
    const float* __restrict__ bw2x, const float* __restrict__ sw2x,
    const float* __restrict__ bb2x, const float* __restrict__ sb2x,
    const float* __restrict__ bw1y, const float* __restrict__ sw1y,
    const float* __restrict__ bb1y, const float* __restrict__ sb1y,
    const float* __restrict__ bw2y, const float* __restrict__ sw2y,
    const float* __restrict__ bb2y, const float* __restrict__ sb2y,
    uint4* __restrict__ B1fx, uint4* __restrict__ B1fy,
    uint4* __restrict__ B2fx, uint4* __restrict__ B2fy,
    float* __restrict__ b1x, float* __restrict__ b1y,
    float* __restrict__ b2x, float* __restrict__ b2y,
    int* __restrict__ cnt)
{
  __shared__ unsigned short stage[9 * 16 * STP];   // [j][dd][o_l], padded

  const int cid = blockIdx.x;
  const int t   = threadIdx.x;

  if (cid < 160) {
    const bool isB1 = (cid < 128);
    int sid, ds, nc, ostr, sstr, ncs;
    const float *bw, *sw;
    uint4* dst;
    if (isB1) {
      sid = cid >> 6; int c = cid & 63; ds = c >> 2; nc = c & 3;
      bw = sid ? bw1y : bw1x; sw = sid ? sw1y : sw1x;
      dst = sid ? B1fy : B1fx;
      ostr = 256; sstr = 2048; ncs = 4;
    } else {
      int c2 = cid - 128; sid = c2 >> 4; int c = c2 & 15; ds = c >> 1; nc = c & 1;
      bw = sid ? bw2y : bw2x; sw = sid ? sw2y : sw2x;
      dst = sid ? B2fy : B2fx;
      ostr = 128; sstr = 1024; ncs = 2;
    }
    // ---- read phase: thread t -> o_l = t>>3, d-pair (t&7)*2 + {0,1} ----
    const int o_l = t >> 3;
    const int o   = nc * 32 + o_l;
    #pragma unroll
    for (int e = 0; e < 2; ++e) {
      int dd = (t & 7) * 2 + e;          // 0..15
      int d  = ds * 16 + dd;
      float bwv = bw[o * ostr + d];
      stage[(0 * 16 + dd) * STP + o_l] = f2bf(bwv);
      const float* sp = sw + (size_t)o * sstr + d * 8;
      float4 s0 = *(const float4*)sp;
      float4 s1 = *(const float4*)(sp + 4);
      stage[(1 * 16 + dd) * STP + o_l] = f2bf(s0.x);
      stage[(2 * 16 + dd) * STP + o_l] = f2bf(s0.y);
      stage[(3 * 16 + dd) * STP + o_l] = f2bf(s0.z);
      stage[(4 * 16 + dd) * STP + o_l] = f2bf(s0.w);
      stage[(5 * 16 + dd) * STP + o_l] = f2bf(s1.x);
      stage[(6 * 16 + dd) * STP + o_l] = f2bf(s1.y);
      stage[(7 * 16 + dd) * STP + o_l] = f2bf(s1.z);
      stage[(8 * 16 + dd) * STP + o_l] = f2bf(s1.w);
    }
    __syncthreads();
    // ---- write phase: 9 slots x 64 uint4, coalesced ----
    for (int u = t; u < 9 * 64; u += 256) {
      int j = u >> 6, l = u & 63;
      int dd0 = (l >> 5) * 8;
      int oL  = l & 31;
      unsigned short e8[8];
      #pragma unroll
      for (int i = 0; i < 8; ++i)
        e8[i] = stage[(j * 16 + dd0 + i) * STP + oL];
      uint4 oh;
      oh.x = (unsigned)e8[0] | ((unsigned)e8[1] << 16);
      oh.y = (unsigned)e8[2] | ((unsigned)e8[3] << 16);
      oh.z = (unsigned)e8[4] | ((unsigned)e8[5] << 16);
      oh.w = (unsigned)e8[6] | ((unsigned)e8[7] << 16);
      int q = (ds * 9 + j) * ncs + nc;
      dst[q * 64 + l] = oh;
    }
  } else {
    // ---- biases + counters ----
    for (int i2 = t; i2 < 388; i2 += 256) {
      if (i2 < 128)      b1x[i2]       = bb1x[i2]       + sb1x[i2];
      else if (i2 < 256) b1y[i2 - 128] = bb1y[i2 - 128] + sb1y[i2 - 128];
      else if (i2 < 320) b2x[i2 - 256] = bb2x[i2 - 256] + sb2x[i2 - 256];
      else if (i2 < 384) b2y[i2 - 320] = bb2y[i2 - 320] + sb2y[i2 - 320];
      else               cnt[i2 - 384] = 0;
    }
  }
}

// ---------- fused: both layers + last-block finish; block = (sid, 32-row tile m)
__global__ __launch_bounds__(512, 2) void fused_kernel(
    const float* __restrict__ Xx, const float* __restrict__ Xy,
    const uint4* __restrict__ B1fx, const uint4* __restrict__ B1fy,
    const uint4* __restrict__ B2fx, const uint4* __restrict__ B2fy,
    const float* __restrict__ b1x_, const float* __restrict__ b1y_,
    const float* __restrict__ b2x_, const float* __restrict__ b2y_,
    const float* __restrict__ finw, const float* __restrict__ finb,
    float* __restrict__ partial, int* __restrict__ cnt,
    float* __restrict__ out)
{
  __shared__ __align__(16) char smem[51232];
  float* xsh  = (float*)smem;               // 32*264 floats = 33792 B
  float* S0   = (float*)smem;               // 16 KB (alias; used after xr read)
  float* S1   = (float*)(smem + 16384);     // 16 KB
  float* h1s  = (float*)(smem + 33792);     // 32*136 floats = 17408 B
  float* redw = (float*)(smem + 51200);     // 8 floats

  const int t    = threadIdx.x;
  const int bid  = blockIdx.x;
  const int sid  = bid >> 7;
  const int m    = bid & 127;
  const int wave = t >> 6;
  const int l    = t & 63;
  const int lc   = l & 31;
  const int lk   = l >> 5;

  const float* X  = sid ? Xy : Xx;
  const uint4* B1 = sid ? B1fy : B1fx;
  const uint4* B2 = sid ? B2fy : B2fx;
  const float* b1 = sid ? b1y_ : b1x_;
  const float* b2 = sid ? b2y_ : b2x_;

  // ---- stage x tile: 32 rows x 256, coalesced ----
  {
    int row = t >> 4, col = (t & 15) * 16;
    const float* src = X + (size_t)(m * 32 + row) * 256 + col;
    #pragma unroll
    for (int q = 0; q < 4; ++q)
      *(float4*)(xsh + row * 264 + col + q * 4) = *(const float4*)(src + q * 4);
  }
  __syncthreads();

  // per-lane A data: row lc, dims for ds0 = 2*wave and ds1 = 2*wave+1
  float xr0[8], xr1[8];
  {
    int cb = wave * 32 + lk * 8;
    float4 v0 = *(const float4*)(xsh + lc * 264 + cb);
    float4 v1 = *(const float4*)(xsh + lc * 264 + cb + 4);
    float4 u0 = *(const float4*)(xsh + lc * 264 + cb + 16);
    float4 u1 = *(const float4*)(xsh + lc * 264 + cb + 20);
    xr0[0]=v0.x; xr0[1]=v0.y; xr0[2]=v0.z; xr0[3]=v0.w;
    xr0[4]=v1.x; xr0[5]=v1.y; xr0[6]=v1.z; xr0[7]=v1.w;
    xr1[0]=u0.x; xr1[1]=u0.y; xr1[2]=u0.z; xr1[3]=u0.w;
    xr1[4]=u1.x; xr1[5]=u1.y; xr1[6]=u1.z; xr1[7]=u1.w;
  }
  __syncthreads();   // xsh dead; S0/S1 free

  // ================= layer 1: 18 steps (9 j x 2 ds), 1-step lookahead ========
  floatx16 acc[4] = {};

  auto loadB1 = [&](int s, uint4* bf) {
    int j = s >> 1, ds = wave * 2 + (s & 1);
    const uint4* bp = B1 + (size_t)((ds * 9 + j) * 4) * 64 + l;
    #pragma unroll
    for (int nc = 0; nc < 4; ++nc) bf[nc] = bp[nc * 64];
  };
  auto computeB1 = [&](int s, const uint4* bf) {
    int j = s >> 1;
    const float* xr = (s & 1) ? xr1 : xr0;
    floatx8 f;
    if (j == 0) {
      #pragma unroll
      for (int i = 0; i < 8; ++i)
        f[i] = __fdividef(xr[i], 1.f + __expf(-xr[i]));
    } else {
      float g = -2.f + (float)(j - 1) * (4.f / 7.f);
      #pragma unroll
      for (int i = 0; i < 8; ++i) {
        float z = (xr[i] - g) * 1.75f;
        f[i] = __expf(-z * z);
      }
    }
    short8 a = __builtin_bit_cast(short8, __builtin_convertvector(f, bf16x8));
    #pragma unroll
    for (int nc = 0; nc < 4; ++nc) {
      short8 bh = __builtin_bit_cast(short8, bf[nc]);
      acc[nc] = __builtin_amdgcn_mfma_f32_32x32x16_bf16(a, bh, acc[nc], 0, 0, 0);
    }
  };

  {
    uint4 bfE[4], bfO[4];
    loadB1(0, bfE);
    #pragma unroll 1
    for (int s = 0; s < 18; s += 2) {
      loadB1(s + 1, bfO);
      computeB1(s, bfE);
      if (s + 2 < 18) loadB1(s + 2, bfE);
      computeB1(s + 1, bfO);
    }
  }

  // ---- cross-wave K reduction: race-free 2-buffer tree (32x128 tile) ----
  auto st = [&](float* Sb) {
    #pragma unroll
    for (int nc = 0; nc < 4; ++nc)
      #pragma unroll
      for (int r = 0; r < 16; ++r) {
        int row = (r & 3) + 8 * (r >> 2) + 4 * lk;
        Sb[row * 128 + nc * 32 + lc] = acc[nc][r];
      }
  };
  auto ad = [&](const float* Sb) {
    #pragma unroll
    for (int nc = 0; nc < 4; ++nc)
      #pragma unroll
      for (int r = 0; r < 16; ++r) {
        int row = (r & 3) + 8 * (r >> 2) + 4 * lk;
        acc[nc][r] += Sb[row * 128 + nc * 32 + lc];
      }
  };
  __syncthreads();
  if (wave == 1) st(S0);
  if (wave == 3) st(S1);
  __syncthreads();
  if (wave == 0) ad(S0);
  if (wave == 2) ad(S1);
  __syncthreads();
  if (wave == 5) st(S0);
  if (wave == 7) st(S1);
  __syncthreads();
  if (wave == 4) ad(S0);
  if (wave == 6) ad(S1);
  __syncthreads();
  if (wave == 2) st(S0);
  if (wave == 6) st(S1);
  __syncthreads();
  if (wave == 0) ad(S0);
  if (wave == 4) ad(S1);
  __syncthreads();
  if (wave == 4) st(S0);
  __syncthreads();
  if (wave == 0) {
    ad(S0);
    #pragma unroll
    for (int nc = 0; nc < 4; ++nc)
      #pragma unroll
      for (int r = 0; r < 16; ++r) {
        int row = (r & 3) + 8 * (r >> 2) + 4 * lk;
        int col = nc * 32 + lc;
        h1s[row * 136 + col] = acc[nc][r] + b1[col];
      }
  }
  __syncthreads();

  // ================= layer 2: 9 steps, 1-step lookahead =================
  floatx16 acc2[2] = {};

  auto loadB2 = [&](int s, uint4* cf) {
    const uint4* bp = B2 + (size_t)((wave * 9 + s) * 2) * 64 + l;
    #pragma unroll
    for (int nc = 0; nc < 2; ++nc) cf[nc] = bp[nc * 64];
  };

  uint4 cfE[2], cfO[2];
  loadB2(0, cfE);              // issue before h1 read; independent

  float hr[8];
  {
    int cb = wave * 16 + lk * 8;
    float4 v0 = *(const float4*)(h1s + lc * 136 + cb);
    float4 v1 = *(const float4*)(h1s + lc * 136 + cb + 4);
    hr[0]=v0.x; hr[1]=v0.y; hr[2]=v0.z; hr[3]=v0.w;
    hr[4]=v1.x; hr[5]=v1.y; hr[6]=v1.z; hr[7]=v1.w;
  }

  auto computeB2 = [&](int s, const uint4* cf) {
    floatx8 f;
    if (s == 0) {
      #pragma unroll
      for (int i = 0; i < 8; ++i)
        f[i] = __fdividef(hr[i], 1.f + __expf(-hr[i]));
    } else {
      float g = -2.f + (float)(s - 1) * (4.f / 7.f);
      #pragma unroll
      for (int i = 0; i < 8; ++i) {
        float z = (hr[i] - g) * 1.75f;
        f[i] = __expf(-z * z);
      }
    }
    short8 a = __builtin_bit_cast(short8, __builtin_convertvector(f, bf16x8));
    #pragma unroll
    for (int nc = 0; nc < 2; ++nc) {
      short8 bh = __builtin_bit_cast(short8, cf[nc]);
      acc2[nc] = __builtin_amdgcn_mfma_f32_32x32x16_bf16(a, bh, acc2[nc], 0, 0, 0);
    }
  };

  #pragma unroll 1
  for (int s = 0; s < 8; s += 2) {
    loadB2(s + 1, cfO);
    computeB2(s, cfE);
    loadB2(s + 2, cfE);
    computeB2(s + 1, cfO);
  }
  computeB2(8, cfE);

  // ---- per-wave dot with final_w; cross-wave scalar sum ----
  const float* wf = finw + sid * 64;
  {
    float w0 = wf[lc], w1v = wf[32 + lc];
    float pz = 0.f;
    #pragma unroll
    for (int r = 0; r < 16; ++r) pz += acc2[0][r] * w0 + acc2[1][r] * w1v;
    #pragma unroll
    for (int off = 32; off > 0; off >>= 1) pz += __shfl_down(pz, off, 64);
    if (l == 0) redw[wave] = pz;
  }
  __syncthreads();

  // ---- block partial + last-block-per-batch finish ----
  if (wave == 0) {
    const int b    = m >> 5;                 // batch
    const int slot = sid * 32 + (m & 31);    // 64 slots per batch
    float v = (l < 8) ? redw[l] : 0.f;
    v += 32.f * b2[l] * wf[l];               // bias term over this block's 32 rows
    #pragma unroll
    for (int off = 32; off > 0; off >>= 1) v += __shfl_down(v, off, 64);
    int old = 0;
    if (l == 0) {
      partial[b * 64 + slot] = v;
      __threadfence();
      old = atomicAdd(&cnt[b], 1);
    }
    int bc = __shfl(old, 0, 64);
    if (bc == 63) {                          // last block of this batch
      float pv = atomicAdd(&partial[b * 64 + l], 0.f);  // coherent read
      #pragma unroll
      for (int off = 32; off > 0; off >>= 1) pv += __shfl_down(pv, off, 64);
      if (l == 0) out[b] = finb[0] + pv * (1.0f / 1024.0f);
    }
  }
}

extern "C" void kernel_launch(void* const* d_in, const int* in_sizes, int n_in,
                              void* d_out, int out_size, void* d_ws, size_t ws_size,
                              hipStream_t stream)
{
  (void)in_sizes; (void)n_in; (void)out_size; (void)ws_size;
  const float* x    = (const float*)d_in[0];
  const float* y    = (const float*)d_in[1];
  const float* bw1x = (const float*)d_in[2];
  const float* bb1x = (const float*)d_in[3];
  const float* sw1x = (const float*)d_in[4];
  const float* sb1x = (const float*)d_in[5];
  const float* bw2x = (const float*)d_in[6];
  const float* bb2x = (const float*)d_in[7];
  const float* sw2x = (const float*)d_in[8];
  const float* sb2x = (const float*)d_in[9];
  const float* bw1y = (const float*)d_in[10];
  const float* bb1y = (const float*)d_in[11];
  const float* sw1y = (const float*)d_in[12];
  const float* sb1y = (const float*)d_in[13];
  const float* bw2y = (const float*)d_in[14];
  const float* bb2y = (const float*)d_in[15];
  const float* sw2y = (const float*)d_in[16];
  const float* sb2y = (const float*)d_in[17];
  const float* finw = (const float*)d_in[18];
  const float* finb = (const float*)d_in[19];

  char* ws = (char*)d_ws;
  uint4* B1fx = (uint4*)(ws);                       // 589824 B
  uint4* B1fy = (uint4*)(ws + 589824);
  uint4* B2fx = (uint4*)(ws + 1179648);             // 147456 B
  uint4* B2fy = (uint4*)(ws + 1327104);
  float* b1x  = (float*)(ws + 1474560);
  float* b1y  = b1x + 128;
  float* b2x  = b1y + 128;
  float* b2y  = b2x + 64;
  float* partial = b2y + 64;                        // 256 floats
  int*   cnt  = (int*)(partial + 256);              // 4 ints

  // prep grid: 128 B1 chunks + 32 B2 chunks + 1 bias block
  hipLaunchKernelGGL(prep_frags, dim3(161), dim3(256), 0, stream,
                     bw1x, sw1x, bb1x, sb1x, bw2x, sw2x, bb2x, sb2x,
                     bw1y, sw1y, bb1y, sb1y, bw2y, sw2y, bb2y, sb2y,
                     B1fx, B1fy, B2fx, B2fy, b1x, b1y, b2x, b2y, cnt);

  hipLaunchKernelGGL(fused_kernel, dim3(256), dim3(512), 0, stream,
                     x, y, B1fx, B1fy, B2fx, B2fy, b1x, b1y, b2x, b2y,
                     finw, finb, partial, cnt, (float*)d_out);
}